// Round 17
// baseline (814.917 us; speedup 1.0000x reference)
//
#include <hip/hip_runtime.h>

typedef short s8v __attribute__((ext_vector_type(8)));
typedef float f4v __attribute__((ext_vector_type(4)));
typedef float f4 __attribute__((ext_vector_type(4)));
typedef unsigned short u16v4 __attribute__((ext_vector_type(4)));

#define N_PIX 16384
#define NE    8192
#define EDIM  256
#define ZQ_ELEMS 4194304
#define MARGIN 4.5e-4f
#define NGRP 512           // 16 codes per pruning group

__device__ __forceinline__ float bf2f(unsigned short u) {
    union { unsigned int i; float f; } c; c.i = ((unsigned int)u) << 16; return c.f;
}
__device__ __forceinline__ unsigned short f2bf(float f) {
    unsigned int u = __float_as_uint(f);
    u = (u + 0x7fffu + ((u >> 16) & 1u)) >> 16;   // RNE
    return (unsigned short)u;
}
__device__ __forceinline__ unsigned short f2bf_down(float f) {  // round toward -inf
    unsigned int u = __float_as_uint(f);
    unsigned short b = (unsigned short)(u >> 16);
    if ((u & 0xFFFFu) && (u >> 31)) b += 1;
    return b;
}

// numpy pairwise_sum over 128 squared elements (exact replication: 8
// accumulators, fixed combine tree), f32 RN ops, no FMA contraction.
__device__ __forceinline__ float np_pw128sq(const float* a) {
    float r[8];
    #pragma unroll
    for (int j = 0; j < 8; ++j) r[j] = __fmul_rn(a[j], a[j]);
    for (int i = 8; i < 128; i += 8)
        #pragma unroll
        for (int j = 0; j < 8; ++j) r[j] = __fadd_rn(r[j], __fmul_rn(a[i + j], a[i + j]));
    return __fadd_rn(__fadd_rn(__fadd_rn(r[0], r[1]), __fadd_rn(r[2], r[3])),
                     __fadd_rn(__fadd_rn(r[4], r[5]), __fadd_rn(r[6], r[7])));
}

// gmin scratch layout: [px_chunk 1024][group 512][px-in-chunk 16] u16.

// K0 (fused): blocks 0..1023 = zprep; blocks 1024..1279 = cb prep.
// Unchanged (proven r7..r16).
__global__ __launch_bounds__(256) void vq_pre(const float* __restrict__ z,
                                              const float* __restrict__ cb,
                                              unsigned short* __restrict__ z16,
                                              unsigned short* __restrict__ cb16,
                                              float* __restrict__ esum32,
                                              int do_z) {
    __shared__ unsigned short zl[64 * 66];
    int t = threadIdx.x;
    int bx = blockIdx.x;
    if (bx < 1024) {
        if (!do_z) return;
        int p0 = (bx >> 2) * 64;             // 64 | 1024: tile in one image
        int c0 = (bx & 3) * 64;
        int b = p0 >> 10, hw0 = p0 & 1023;
        const float* src = z + (((size_t)b * 256 + c0) << 10) + hw0;
        #pragma unroll
        for (int i = 0; i < 4; ++i) {
            int idx = i * 256 + t;           // 1024 jobs: 64 ch x 16 px-quads
            int ch = idx >> 4, pq = idx & 15;
            f4 v = *(const f4*)(src + ((size_t)ch << 10) + pq * 4);
            #pragma unroll
            for (int e = 0; e < 4; ++e) zl[(pq * 4 + e) * 66 + ch] = f2bf(v[e]);
        }
        __syncthreads();
        #pragma unroll
        for (int i = 0; i < 2; ++i) {
            int idx = i * 256 + t;           // 512 jobs: 64 px x 8 ch-chunks
            int px = idx >> 3, cc = idx & 7;
            s8v o;
            #pragma unroll
            for (int e = 0; e < 8; ++e) o[e] = (short)zl[px * 66 + cc * 8 + e];
            *(s8v*)&z16[((size_t)(p0 + px)) * 256 + c0 + cc * 8] = o;
        }
    } else {
        int base = (bx - 1024) * 32;         // 256 blocks x 32 rows
        const float* src = cb + (size_t)base * EDIM;
        unsigned short* dst = cb16 + (size_t)base * EDIM;
        #pragma unroll
        for (int i = 0; i < 8; ++i) {
            int e0 = (i * 256 + t) * 4;
            f4 v = *(const f4*)(src + e0);
            u16v4 o;
            o.x = f2bf(v[0]); o.y = f2bf(v[1]); o.z = f2bf(v[2]); o.w = f2bf(v[3]);
            *(u16v4*)(dst + e0) = o;
        }
        if (t < 32) {
            const float* a = cb + (size_t)(base + t) * EDIM;
            esum32[base + t] = __fadd_rn(np_pw128sq(a), np_pw128sq(a + 128));
        }
    }
}

// K1: 256-code x 1024-px persistent GEMM, BK=32, DOUBLE OCCUPANCY.
// r16 post-mortem: at 128KB LDS the kernel ran 1 block/CU; the per-iter
// vmcnt+barrier rendezvous had NOTHING co-resident to hide it -> 84% stall
// (7500 cyc/iter vs ~600 cyc pipe work). This is the guide's m132/m114
// finding: block-level overlap needs >=2 blocks/CU. BK 64->32 halves LDS
// to 64KB (2 blocks/CU, 16 waves), grid 256->512 (32 cm x 16 pg of 1024px;
// bx%8==pg%8 keeps XCD L2 mapping, 2x512KB B panels per L2). Per-iter:
// stage next K-slice (4 GLL) -> 12 frag b128 reads -> 32 MFMA ->
// vmcnt(0)+barrier. Per-half staging geometry / involution swizzle / read
// offsets identical to the verified r14 half-layout; K advances in the
// SAME ascending 32-chunk order with the same f2bf inputs -> gmin
// bit-identical. launch_bounds(512,4): VGPR cap 128 >= current 104.
__global__ __launch_bounds__(512, 4) void vq_phase1g(const unsigned short* __restrict__ cb16,
                                                     const unsigned short* __restrict__ z16,
                                                     unsigned short* __restrict__ gmin) {
    __shared__ unsigned short L[2][16384];   // [buf][A 8K u16 | B 8K u16] = 64 KB
    const int t = threadIdx.x;
    const int wave = t >> 6, lane = t & 63;
    const int q = lane >> 4, r = lane & 15;
    const int wr = wave >> 2, wc = wave & 3;      // 2 M-waves x 4 N-waves
    const int cm0 = ((int)blockIdx.x >> 4) * 256; // code tile (32 of them)
    const int pg  = (int)blockIdx.x & 15;         // px-group (16 of 1024 px)

    // Staging: one operand slice = 256 rows x 32 k = 16 KB = 1024 chunks
    // of 16B; 2 chunks/thread. Physical chunk pc=(row,cph) holds logical
    // chunk lc = cph ^ ((row>>1)&3)  (involution, verified r14).
    const int pc0 = t, pc1 = t + 512;
    const int row0 = pc0 >> 2, row1 = pc1 >> 2;
    const int lc0 = (pc0 & 3) ^ ((row0 >> 1) & 3);
    const int lc1 = (pc1 & 3) ^ ((row1 >> 1) & 3);
    const int go0 = row0 * 256 + lc0 * 8;   // u16; + gk
    const int go1 = row1 * 256 + lc1 * 8;
    const int ld0 = pc0 * 8;                // u16 within operand region
    const int ld1 = pc1 * 8;

    const unsigned short* gA = cb16 + (size_t)cm0 * 256;
    const unsigned short* gB0 = z16 + (size_t)pg * 1024 * 256;  // px-group base

    f4v acc[8][4];
    const f4v zz = {0.f, 0.f, 0.f, 0.f};
    #pragma unroll
    for (int mi = 0; mi < 8; ++mi)
        #pragma unroll
        for (int ni = 0; ni < 4; ++ni) acc[mi][ni] = zz;

    const int cxo = (q ^ ((r >> 1) & 3)) * 8;     // swizzled chunk offset (u16)
    const int aro = (wr * 128 + r) * 32 + cxo;    // A frag base (+mi*512)
    const int bro = 8192 + (wc * 64 + r) * 32 + cxo; // B frag base (+ni*512)

#define GLL(g, l) __builtin_amdgcn_global_load_lds( \
        (const __attribute__((address_space(1))) unsigned int*)(g), \
        (__attribute__((address_space(3))) unsigned int*)(l), 16, 0, 0)
#define STAGEKT(buf_, gk_, gBp_) do { \
        unsigned short* Lb_ = &L[(buf_)][0]; \
        GLL(gA + go0 + (gk_),      Lb_ + ld0); \
        GLL(gA + go1 + (gk_),      Lb_ + ld1); \
        GLL((gBp_) + go0 + (gk_),  Lb_ + 8192 + ld0); \
        GLL((gBp_) + go1 + (gk_),  Lb_ + 8192 + ld1); } while (0)
#define ARD(Lp, mi) (*(const s8v*)&(Lp)[(mi) * 512 + aro])
#define BRD(Lp, ni) (*(const s8v*)&(Lp)[(ni) * 512 + bro])

    // prologue: stage iteration 0 into buf0, drain once, sync.
    STAGEKT(0, 0, gB0);
    asm volatile("s_waitcnt vmcnt(0)" ::: "memory");
    __builtin_amdgcn_s_barrier();

    for (int it = 0; it < 32; ++it) {             // it = px*8 + kt
        const int buf = it & 1;
        const unsigned short* Lb = &L[buf][0];
        const int nit = it + 1;
        const bool st = nit < 32;

        // stage next K-slice into buf^1 (WAR safe: buf^1 readers finished
        // before the previous iteration's tail barrier).
        if (st) STAGEKT(buf ^ 1, (nit & 7) * 32,
                        gB0 + (size_t)(nit >> 3) * 65536);

        s8v A0[4], A1[4], B0[4];
        #pragma unroll
        for (int ni = 0; ni < 4; ++ni) B0[ni] = BRD(Lb, ni);
        #pragma unroll
        for (int mi = 0; mi < 4; ++mi) A0[mi] = ARD(Lb, mi);
        #pragma unroll
        for (int mi = 0; mi < 4; ++mi) A1[mi] = ARD(Lb, 4 + mi);
        __builtin_amdgcn_sched_barrier(0);
        __builtin_amdgcn_s_setprio(1);
        #pragma unroll
        for (int mi = 0; mi < 4; ++mi)
            #pragma unroll
            for (int ni = 0; ni < 4; ++ni)
                acc[mi][ni] = __builtin_amdgcn_mfma_f32_16x16x32_bf16(
                    A0[mi], B0[ni], acc[mi][ni], 0, 0, 0);
        #pragma unroll
        for (int mi = 0; mi < 4; ++mi)
            #pragma unroll
            for (int ni = 0; ni < 4; ++ni)
                acc[4 + mi][ni] = __builtin_amdgcn_mfma_f32_16x16x32_bf16(
                    A1[mi], B0[ni], acc[4 + mi][ni], 0, 0, 0);
        __builtin_amdgcn_s_setprio(0);

        // tail gate: buf^1's 4 loads landed; all waves' reads of buf done.
        asm volatile("s_waitcnt vmcnt(0)" ::: "memory");
        __builtin_amdgcn_s_barrier();

        // px-tile boundary: emit group-maxes, reset acc. Wave-local.
        if ((it & 7) == 7) {
            const int pn0 = pg * 1024 + (it >> 3) * 256;
            #pragma unroll
            for (int mi = 0; mi < 8; ++mi) {
                int g = cm0 / 16 + wr * 8 + mi;
                #pragma unroll
                for (int ni = 0; ni < 4; ++ni) {
                    f4v a = acc[mi][ni];
                    float mx = fmaxf(fmaxf(a[0], a[1]), fmaxf(a[2], a[3]));
                    mx = fmaxf(mx, __shfl_xor(mx, 16));
                    mx = fmaxf(mx, __shfl_xor(mx, 32));
                    if (q == 0) {
                        int pxc = (pn0 + wc * 64 + ni * 16) >> 4;
                        gmin[(size_t)pxc * 8192 + g * 16 + r] = f2bf_down(-2.0f * mx);
                    }
                    acc[mi][ni] = zz;
                }
            }
        }
    }
#undef BRD
#undef ARD
#undef STAGEKT
#undef GLL
}

// K1 (fallback): used only if workspace can't hold z16.
__global__ __launch_bounds__(512, 2) void vq_phase1(const float* __restrict__ z,
                                                    const unsigned short* __restrict__ cb16,
                                                    unsigned short* __restrict__ gmin) {
    const int t = threadIdx.x;
    const int wave = t >> 6, lane = t & 63;
    const int col = lane & 15, q = lane >> 4;
    const int mb = (blockIdx.x >> 1) * 64;
    const int chalf = blockIdx.x & 1;

    s8v Z[4][8];
    #pragma unroll
    for (int pt = 0; pt < 4; ++pt) {
        int n = mb + pt * 16 + col;
        const float* zb = z + ((size_t)(n >> 10) << 18) + (size_t)(n & 1023);
        #pragma unroll
        for (int c0 = 0; c0 < 8; ++c0) {
            s8v a;
            #pragma unroll
            for (int j = 0; j < 8; ++j) {
                int c = c0 * 32 + q * 8 + j;
                a[j] = (short)f2bf(zb[(size_t)c << 10]);
            }
            Z[pt][c0] = a;
        }
    }

    const int kbase = chalf * 4096 + wave * 512;
    for (int it = 0; it < 16; ++it) {
        int n0 = kbase + it * 32;
        const unsigned short* bb = cb16 + (size_t)(n0 + col) * EDIM + q * 8;
        f4v zz = {0.f, 0.f, 0.f, 0.f};
        f4v acc[4][2];
        #pragma unroll
        for (int pt = 0; pt < 4; ++pt) { acc[pt][0] = zz; acc[pt][1] = zz; }
        #pragma unroll
        for (int c0 = 0; c0 < 8; ++c0) {
            s8v C0 = *(const s8v*)(bb + c0 * 32);
            s8v C1 = *(const s8v*)(bb + 16 * EDIM + c0 * 32);
            #pragma unroll
            for (int pt = 0; pt < 4; ++pt) {
                acc[pt][0] = __builtin_amdgcn_mfma_f32_16x16x32_bf16(C0, Z[pt][c0], acc[pt][0], 0, 0, 0);
                acc[pt][1] = __builtin_amdgcn_mfma_f32_16x16x32_bf16(C1, Z[pt][c0], acc[pt][1], 0, 0, 0);
            }
        }
        int gbase = chalf * 256 + wave * 32 + it * 2;
        #pragma unroll
        for (int pt = 0; pt < 4; ++pt) {
            #pragma unroll
            for (int s = 0; s < 2; ++s) {
                f4v a = acc[pt][s];
                float mx = fmaxf(fmaxf(a[0], a[1]), fmaxf(a[2], a[3]));
                mx = fmaxf(mx, __shfl_xor(mx, 16));
                mx = fmaxf(mx, __shfl_xor(mx, 32));
                if (q == 0)
                    gmin[(size_t)((mb >> 4) + pt) * 8192 + (gbase + s) * 16 + col] =
                        f2bf_down(-2.0f * mx);
            }
        }
    }
}

// K2: rescore + fused loss (r16 proven version, UNCHANGED).
__global__ __launch_bounds__(256) void vq_phase2(const float* __restrict__ z,
                                                 const float* __restrict__ cb,
                                                 const float* __restrict__ esum32,
                                                 const unsigned short* __restrict__ gmin,
                                                 unsigned int* __restrict__ idxw,
                                                 float* __restrict__ lossparts) {
    __shared__ float zt[32 * 260];
    __shared__ unsigned short gm[NGRP * 33];
    __shared__ float zs[32];
    __shared__ int pq;
    int t = threadIdx.x;
    int wave = t >> 6, lane = t & 63;
    int p0 = blockIdx.x * 32;
    int bb = p0 >> 10, inner = p0 & 1023;

    if (t == 0) pq = 0;
    const float* zb = z + (((size_t)bb * 256) << 10) + inner;
    #pragma unroll
    for (int i = 0; i < 8; ++i) {
        int job = i * 256 + t;
        int c = job >> 3, qq = job & 7;      // 8 threads cover one 128B row
        f4 v = *(const f4*)(zb + ((size_t)c << 10) + qq * 4);
        #pragma unroll
        for (int e = 0; e < 4; ++e) zt[(qq * 4 + e) * 260 + c] = v[e];
    }
    const unsigned short* gsrc = gmin + (size_t)(2 * blockIdx.x) * 8192;
    #pragma unroll
    for (int j = 0; j < 8; ++j) {
        int li8 = (j * 256 + t) * 8;         // u16 offset, 16B-aligned, <16384
        s8v v = *(const s8v*)(gsrc + li8);
        int h = li8 >> 13, rem = li8 & 8191; // h in {0,1}
        int g = rem >> 4, r0 = rem & 15;     // r0 in {0,8}
        #pragma unroll
        for (int e = 0; e < 8; ++e) gm[g * 33 + h * 16 + r0 + e] = (unsigned short)v[e];
    }
    __syncthreads();
    if (t < 32) {
        const float* a = zt + t * 260;
        zs[t] = __fadd_rn(np_pw128sq(a), np_pw128sq(a + 128));  // np zsum
    }
    __syncthreads();

#define DOT_TAIL(sv) do { sv += __shfl_xor(sv, 1); sv += __shfl_xor(sv, 2); } while (0)
#define MERGE(dv, kv) do { if ((dv) < bd || ((dv) == bd && (kv) < bk)) { bd = (dv); bk = (kv); } } while (0)

    float wls = 0.f;                          // per-lane loss partial
    while (true) {
        int p;
        if (lane == 0) p = atomicAdd(&pq, 1);
        p = __shfl(p, 0);
        if (p >= 32) break;

        float lmin = 3.0e38f;
        #pragma unroll
        for (int j = 0; j < 8; ++j) lmin = fminf(lmin, bf2f(gm[(lane * 8 + j) * 33 + p]));
        #pragma unroll
        for (int m = 1; m < 64; m <<= 1) lmin = fminf(lmin, __shfl_xor(lmin, m));
        float thr = lmin + MARGIN;
        float zsp = zs[p];
        const f4* zr = (const f4*)(zt + p * 260) + (lane & 3);

        float bd = 3.0e38f; int bk = 0x7FFFFFFF;
        int pend = -1;
        for (int j = 0; j < 8; ++j) {
            unsigned long long mask = __ballot(bf2f(gm[(lane * 8 + j) * 33 + p]) <= thr);
            while (mask) {
                int lb = __builtin_ctzll(mask); mask &= mask - 1;
                int g = lb * 8 + j;
                if (pend < 0) { pend = g; continue; }
                int k1 = pend * 16 + (lane >> 2), k2 = g * 16 + (lane >> 2);
                const f4* c1 = (const f4*)(cb + (size_t)k1 * EDIM) + (lane & 3);
                const f4* c2 = (const f4*)(cb + (size_t)k2 * EDIM) + (lane & 3);
                double a0 = 0.0, a1 = 0.0, a2 = 0.0, a3 = 0.0;
                double b0 = 0.0, b1 = 0.0, b2 = 0.0, b3 = 0.0;
                #pragma unroll
                for (int i = 0; i < 16; ++i) {
                    f4 x = zr[i * 4], y1 = c1[i * 4], y2 = c2[i * 4];
                    a0 = fma((double)x[0], (double)y1[0], a0);
                    b0 = fma((double)x[0], (double)y2[0], b0);
                    a1 = fma((double)x[1], (double)y1[1], a1);
                    b1 = fma((double)x[1], (double)y2[1], b1);
                    a2 = fma((double)x[2], (double)y1[2], a2);
                    b2 = fma((double)x[2], (double)y2[2], b2);
                    a3 = fma((double)x[3], (double)y1[3], a3);
                    b3 = fma((double)x[3], (double)y2[3], b3);
                }
                double s1 = (a0 + a1) + (a2 + a3);
                double s2 = (b0 + b1) + (b2 + b3);
                DOT_TAIL(s1); DOT_TAIL(s2);
                float E1 = (float)s1, E2 = (float)s2;
                float d1 = __fsub_rn(__fadd_rn(zsp, esum32[k1]), __fmul_rn(2.0f, E1));
                float d2 = __fsub_rn(__fadd_rn(zsp, esum32[k2]), __fmul_rn(2.0f, E2));
                MERGE(d1, k1); MERGE(d2, k2);
                pend = -1;
            }
        }
        if (pend >= 0) {   // leftover single rescore (exact r6 body)
            int k = pend * 16 + (lane >> 2);
            const f4* cr = (const f4*)(cb + (size_t)k * EDIM) + (lane & 3);
            double a0 = 0.0, a1 = 0.0, a2 = 0.0, a3 = 0.0;
            #pragma unroll
            for (int i = 0; i < 16; ++i) {
                f4 x = zr[i * 4], y = cr[i * 4];
                a0 = fma((double)x[0], (double)y[0], a0);
                a1 = fma((double)x[1], (double)y[1], a1);
                a2 = fma((double)x[2], (double)y[2], a2);
                a3 = fma((double)x[3], (double)y[3], a3);
            }
            double s = (a0 + a1) + (a2 + a3);
            DOT_TAIL(s);
            float E = (float)s;
            float d = __fsub_rn(__fadd_rn(zsp, esum32[k]), __fmul_rn(2.0f, E));
            MERGE(d, k);
        }
        #pragma unroll
        for (int m = 1; m < 64; m <<= 1) {
            float od = __shfl_xor(bd, m); int ok = __shfl_xor(bk, m);
            if (od < bd || (od == bd && ok < bk)) { bd = od; bk = ok; }
        }
        if (lane == 0) idxw[p0 + p] = (unsigned int)bk;

        float s0 = 0.f;
        #pragma unroll
        for (int e = 0; e < 4; ++e) {
            float cv = cb[(size_t)bk * EDIM + lane + 64 * e];
            float zv = zt[p * 260 + lane + 64 * e];
            float dx = cv - zv; s0 = fmaf(dx, dx, s0);
        }
        wls += s0;
    }
    #pragma unroll
    for (int m = 1; m < 64; m <<= 1) wls += __shfl_xor(wls, m);
    if (lane == 0)
        atomicAdd(&lossparts[(((int)blockIdx.x << 2) + wave) & 63], wls);
#undef MERGE
#undef DOT_TAIL
}

// K3: pure scatter (r16 proven, UNCHANGED): z_q, indices, loss scalar.
__global__ __launch_bounds__(256) void vq_emit(const float* __restrict__ cb,
                                               const unsigned int* __restrict__ idxw,
                                               const float* __restrict__ lossparts,
                                               float* __restrict__ outf) {
    __shared__ float qrow[1024 * 17];        // [p][16ch] pad 17
    __shared__ unsigned int lidx[1024];
    int t = threadIdx.x;
    int gtid = blockIdx.x * 256 + t;
    if (gtid < N_PIX) outf[ZQ_ELEMS + 1 + gtid] = (float)(idxw[gtid] & (NE - 1));
    if (blockIdx.x == 0 && t < 64) {
        double v = (double)lossparts[t];
        #pragma unroll
        for (int m = 1; m < 64; m <<= 1) v += __shfl_xor(v, m);
        if (t == 0) outf[ZQ_ELEMS] = 1.25f * (float)(v * (1.0 / 4194304.0));
    }

    int b = blockIdx.x >> 4;                 // image
    int c0 = (blockIdx.x & 15) * 16;         // channel chunk

    #pragma unroll
    for (int j = 0; j < 4; ++j)
        lidx[j * 256 + t] = idxw[b * 1024 + j * 256 + t] & (NE - 1);
    __syncthreads();
    #pragma unroll
    for (int j = 0; j < 16; ++j) {
        int p = j * 64 + (t >> 2);
        f4 v = *(const f4*)(cb + (size_t)lidx[p] * EDIM + c0 + (t & 3) * 4);
        #pragma unroll
        for (int e = 0; e < 4; ++e) qrow[p * 17 + (t & 3) * 4 + e] = v[e];
    }
    __syncthreads();

    size_t base = (size_t)blockIdx.x * 16384;
    #pragma unroll
    for (int i = 0; i < 16; ++i) {           // ch chunk i, px = t*4..t*4+3
        f4 v;
        #pragma unroll
        for (int e = 0; e < 4; ++e) v[e] = qrow[(t * 4 + e) * 17 + i];
        *(f4*)&outf[base + (size_t)i * 1024 + t * 4] = v;
    }
}

extern "C" void kernel_launch(void* const* d_in, const int* in_sizes, int n_in,
                              void* d_out, int out_size, void* d_ws, size_t ws_size,
                              hipStream_t stream) {
    const float* z  = (const float*)d_in[0];   // f32 [16,256,32,32]
    const float* cb = (const float*)d_in[1];   // f32 [8192,256]
    float* outf = (float*)d_out;               // f32 [z_q | loss | indices]
    // gmin scratch (1024 chunks x 512 g x 16 px, u16 = 16.78 MB) lives in the
    // z_q chunk of d_out between phase1 and phase2; vq_emit overwrites it.
    unsigned short* gmin = (unsigned short*)d_out;

    char* w = (char*)d_ws;
    unsigned short* cb16     = (unsigned short*)w;             //  4,194,304 B
    float*          esum32   = (float*)(w + 4194304);          //     32,768 B
    unsigned int*   idxw     = (unsigned int*)(w + 4227072);   //     65,536 B
    float*          lossparts= (float*)(w + 4292608);          //        256 B (64 f32)
    unsigned short* z16      = (unsigned short*)(w + 4292864); //  8,388,608 B -> 12,681,472

    if (ws_size < 4292864) return;  // diagnostic: all-zero out => ws too small
    const bool big_ws = (ws_size >= 12681472);

    hipMemsetAsync(lossparts, 0, 256, stream);
    vq_pre<<<1280, 256, 0, stream>>>(z, cb, z16, cb16, esum32, big_ws ? 1 : 0);
    if (big_ws) {
        vq_phase1g<<<(NE / 256) * (N_PIX / 1024), 512, 0, stream>>>(cb16, z16, gmin);
    } else {
        vq_phase1 <<<(N_PIX / 64) * 2, 512, 0, stream>>>(z, cb16, gmin);
    }
    vq_phase2  <<<N_PIX / 32, 256, 0, stream>>>(z, cb, esum32, gmin, idxw, lossparts);
    vq_emit    <<<256, 256, 0, stream>>>(cb, idxw, lossparts, outf);
}

// Round 18
// 232.149 us; speedup vs baseline: 3.5103x; 3.5103x over previous
//
#include <hip/hip_runtime.h>

typedef short s8v __attribute__((ext_vector_type(8)));
typedef float f4v __attribute__((ext_vector_type(4)));
typedef float f4 __attribute__((ext_vector_type(4)));
typedef unsigned short u16v4 __attribute__((ext_vector_type(4)));

#define N_PIX 16384
#define NE    8192
#define EDIM  256
#define ZQ_ELEMS 4194304
#define MARGIN 4.5e-4f
#define NGRP 512           // 16 codes per pruning group

__device__ __forceinline__ float bf2f(unsigned short u) {
    union { unsigned int i; float f; } c; c.i = ((unsigned int)u) << 16; return c.f;
}
__device__ __forceinline__ unsigned short f2bf(float f) {
    unsigned int u = __float_as_uint(f);
    u = (u + 0x7fffu + ((u >> 16) & 1u)) >> 16;   // RNE
    return (unsigned short)u;
}
__device__ __forceinline__ unsigned short f2bf_down(float f) {  // round toward -inf
    unsigned int u = __float_as_uint(f);
    unsigned short b = (unsigned short)(u >> 16);
    if ((u & 0xFFFFu) && (u >> 31)) b += 1;
    return b;
}

// numpy pairwise_sum over 128 squared elements (exact replication: 8
// accumulators, fixed combine tree), f32 RN ops, no FMA contraction.
__device__ __forceinline__ float np_pw128sq(const float* a) {
    float r[8];
    #pragma unroll
    for (int j = 0; j < 8; ++j) r[j] = __fmul_rn(a[j], a[j]);
    for (int i = 8; i < 128; i += 8)
        #pragma unroll
        for (int j = 0; j < 8; ++j) r[j] = __fadd_rn(r[j], __fmul_rn(a[i + j], a[i + j]));
    return __fadd_rn(__fadd_rn(__fadd_rn(r[0], r[1]), __fadd_rn(r[2], r[3])),
                     __fadd_rn(__fadd_rn(r[4], r[5]), __fadd_rn(r[6], r[7])));
}

// gmin scratch layout: [px_chunk 1024][group 512][px-in-chunk 16] u16.

// K0 (fused): blocks 0..1023 = zprep; blocks 1024..1279 = cb prep.
// r18: block 1024 also zeroes lossparts (replaces the hipMemsetAsync
// dispatch; stream order guarantees it precedes phase2's atomics).
__global__ __launch_bounds__(256) void vq_pre(const float* __restrict__ z,
                                              const float* __restrict__ cb,
                                              unsigned short* __restrict__ z16,
                                              unsigned short* __restrict__ cb16,
                                              float* __restrict__ esum32,
                                              float* __restrict__ lossparts,
                                              int do_z) {
    __shared__ unsigned short zl[64 * 66];
    int t = threadIdx.x;
    int bx = blockIdx.x;
    if (bx < 1024) {
        if (!do_z) return;
        int p0 = (bx >> 2) * 64;             // 64 | 1024: tile in one image
        int c0 = (bx & 3) * 64;
        int b = p0 >> 10, hw0 = p0 & 1023;
        const float* src = z + (((size_t)b * 256 + c0) << 10) + hw0;
        #pragma unroll
        for (int i = 0; i < 4; ++i) {
            int idx = i * 256 + t;           // 1024 jobs: 64 ch x 16 px-quads
            int ch = idx >> 4, pq = idx & 15;
            f4 v = *(const f4*)(src + ((size_t)ch << 10) + pq * 4);
            #pragma unroll
            for (int e = 0; e < 4; ++e) zl[(pq * 4 + e) * 66 + ch] = f2bf(v[e]);
        }
        __syncthreads();
        #pragma unroll
        for (int i = 0; i < 2; ++i) {
            int idx = i * 256 + t;           // 512 jobs: 64 px x 8 ch-chunks
            int px = idx >> 3, cc = idx & 7;
            s8v o;
            #pragma unroll
            for (int e = 0; e < 8; ++e) o[e] = (short)zl[px * 66 + cc * 8 + e];
            *(s8v*)&z16[((size_t)(p0 + px)) * 256 + c0 + cc * 8] = o;
        }
    } else {
        if (bx == 1024 && t < 64) lossparts[t] = 0.f;
        int base = (bx - 1024) * 32;         // 256 blocks x 32 rows
        const float* src = cb + (size_t)base * EDIM;
        unsigned short* dst = cb16 + (size_t)base * EDIM;
        #pragma unroll
        for (int i = 0; i < 8; ++i) {
            int e0 = (i * 256 + t) * 4;
            f4 v = *(const f4*)(src + e0);
            u16v4 o;
            o.x = f2bf(v[0]); o.y = f2bf(v[1]); o.z = f2bf(v[2]); o.w = f2bf(v[3]);
            *(u16v4*)(dst + e0) = o;
        }
        if (t < 32) {
            const float* a = cb + (size_t)(base + t) * EDIM;
            esum32[base + t] = __fadd_rn(np_pw128sq(a), np_pw128sq(a + 128));
        }
    }
}

// K1: 256-code x 1024-px persistent GEMM, BK=32, 64KB LDS.
// r17 post-mortem: __launch_bounds__(512,4) forced VGPR=64 < the 128-reg
// accumulator file -> scratch spill (2 GB writes, 677us). FIX: (512,2)
// (VGPR budget 256; body allocates ~104 naturally). If the allocator
// lands <=128, the HARDWARE still co-schedules 2 blocks/CU (LDS 2x64KB
// fits 160KB; 16 waves x 128 VGPR fits) -- launch_bounds is a floor, not
// a cap. Worst case degrades to 1 block/CU ~= r16's 100us, not a spill.
// Geometry/swizzle/K-order identical to r17 (r14-derived) -> gmin
// bit-identical.
__global__ __launch_bounds__(512, 2) void vq_phase1g(const unsigned short* __restrict__ cb16,
                                                     const unsigned short* __restrict__ z16,
                                                     unsigned short* __restrict__ gmin) {
    __shared__ unsigned short L[2][16384];   // [buf][A 8K u16 | B 8K u16] = 64 KB
    const int t = threadIdx.x;
    const int wave = t >> 6, lane = t & 63;
    const int q = lane >> 4, r = lane & 15;
    const int wr = wave >> 2, wc = wave & 3;      // 2 M-waves x 4 N-waves
    const int cm0 = ((int)blockIdx.x >> 4) * 256; // code tile (32 of them)
    const int pg  = (int)blockIdx.x & 15;         // px-group (16 of 1024 px)

    const int pc0 = t, pc1 = t + 512;
    const int row0 = pc0 >> 2, row1 = pc1 >> 2;
    const int lc0 = (pc0 & 3) ^ ((row0 >> 1) & 3);
    const int lc1 = (pc1 & 3) ^ ((row1 >> 1) & 3);
    const int go0 = row0 * 256 + lc0 * 8;   // u16; + gk
    const int go1 = row1 * 256 + lc1 * 8;
    const int ld0 = pc0 * 8;                // u16 within operand region
    const int ld1 = pc1 * 8;

    const unsigned short* gA = cb16 + (size_t)cm0 * 256;
    const unsigned short* gB0 = z16 + (size_t)pg * 1024 * 256;  // px-group base

    f4v acc[8][4];
    const f4v zz = {0.f, 0.f, 0.f, 0.f};
    #pragma unroll
    for (int mi = 0; mi < 8; ++mi)
        #pragma unroll
        for (int ni = 0; ni < 4; ++ni) acc[mi][ni] = zz;

    const int cxo = (q ^ ((r >> 1) & 3)) * 8;     // swizzled chunk offset (u16)
    const int aro = (wr * 128 + r) * 32 + cxo;    // A frag base (+mi*512)
    const int bro = 8192 + (wc * 64 + r) * 32 + cxo; // B frag base (+ni*512)

#define GLL(g, l) __builtin_amdgcn_global_load_lds( \
        (const __attribute__((address_space(1))) unsigned int*)(g), \
        (__attribute__((address_space(3))) unsigned int*)(l), 16, 0, 0)
#define STAGEKT(buf_, gk_, gBp_) do { \
        unsigned short* Lb_ = &L[(buf_)][0]; \
        GLL(gA + go0 + (gk_),      Lb_ + ld0); \
        GLL(gA + go1 + (gk_),      Lb_ + ld1); \
        GLL((gBp_) + go0 + (gk_),  Lb_ + 8192 + ld0); \
        GLL((gBp_) + go1 + (gk_),  Lb_ + 8192 + ld1); } while (0)
#define ARD(Lp, mi) (*(const s8v*)&(Lp)[(mi) * 512 + aro])
#define BRD(Lp, ni) (*(const s8v*)&(Lp)[(ni) * 512 + bro])

    // prologue: stage iteration 0 into buf0, drain once, sync.
    STAGEKT(0, 0, gB0);
    asm volatile("s_waitcnt vmcnt(0)" ::: "memory");
    __builtin_amdgcn_s_barrier();

    for (int it = 0; it < 32; ++it) {             // it = px*8 + kt
        const int buf = it & 1;
        const unsigned short* Lb = &L[buf][0];
        const int nit = it + 1;
        const bool st = nit < 32;

        // stage next K-slice into buf^1 (WAR safe: buf^1 readers finished
        // before the previous iteration's tail barrier).
        if (st) STAGEKT(buf ^ 1, (nit & 7) * 32,
                        gB0 + (size_t)(nit >> 3) * 65536);

        s8v A0[4], A1[4], B0[4];
        #pragma unroll
        for (int ni = 0; ni < 4; ++ni) B0[ni] = BRD(Lb, ni);
        #pragma unroll
        for (int mi = 0; mi < 4; ++mi) A0[mi] = ARD(Lb, mi);
        #pragma unroll
        for (int mi = 0; mi < 4; ++mi) A1[mi] = ARD(Lb, 4 + mi);
        __builtin_amdgcn_sched_barrier(0);
        __builtin_amdgcn_s_setprio(1);
        #pragma unroll
        for (int mi = 0; mi < 4; ++mi)
            #pragma unroll
            for (int ni = 0; ni < 4; ++ni)
                acc[mi][ni] = __builtin_amdgcn_mfma_f32_16x16x32_bf16(
                    A0[mi], B0[ni], acc[mi][ni], 0, 0, 0);
        #pragma unroll
        for (int mi = 0; mi < 4; ++mi)
            #pragma unroll
            for (int ni = 0; ni < 4; ++ni)
                acc[4 + mi][ni] = __builtin_amdgcn_mfma_f32_16x16x32_bf16(
                    A1[mi], B0[ni], acc[4 + mi][ni], 0, 0, 0);
        __builtin_amdgcn_s_setprio(0);

        // tail gate: buf^1's 4 loads landed; all waves' reads of buf done.
        asm volatile("s_waitcnt vmcnt(0)" ::: "memory");
        __builtin_amdgcn_s_barrier();

        // px-tile boundary: emit group-maxes, reset acc. Wave-local.
        if ((it & 7) == 7) {
            const int pn0 = pg * 1024 + (it >> 3) * 256;
            #pragma unroll
            for (int mi = 0; mi < 8; ++mi) {
                int g = cm0 / 16 + wr * 8 + mi;
                #pragma unroll
                for (int ni = 0; ni < 4; ++ni) {
                    f4v a = acc[mi][ni];
                    float mx = fmaxf(fmaxf(a[0], a[1]), fmaxf(a[2], a[3]));
                    mx = fmaxf(mx, __shfl_xor(mx, 16));
                    mx = fmaxf(mx, __shfl_xor(mx, 32));
                    if (q == 0) {
                        int pxc = (pn0 + wc * 64 + ni * 16) >> 4;
                        gmin[(size_t)pxc * 8192 + g * 16 + r] = f2bf_down(-2.0f * mx);
                    }
                    acc[mi][ni] = zz;
                }
            }
        }
    }
#undef BRD
#undef ARD
#undef STAGEKT
#undef GLL
}

// K1 (fallback): used only if workspace can't hold z16.
__global__ __launch_bounds__(512, 2) void vq_phase1(const float* __restrict__ z,
                                                    const unsigned short* __restrict__ cb16,
                                                    unsigned short* __restrict__ gmin) {
    const int t = threadIdx.x;
    const int wave = t >> 6, lane = t & 63;
    const int col = lane & 15, q = lane >> 4;
    const int mb = (blockIdx.x >> 1) * 64;
    const int chalf = blockIdx.x & 1;

    s8v Z[4][8];
    #pragma unroll
    for (int pt = 0; pt < 4; ++pt) {
        int n = mb + pt * 16 + col;
        const float* zb = z + ((size_t)(n >> 10) << 18) + (size_t)(n & 1023);
        #pragma unroll
        for (int c0 = 0; c0 < 8; ++c0) {
            s8v a;
            #pragma unroll
            for (int j = 0; j < 8; ++j) {
                int c = c0 * 32 + q * 8 + j;
                a[j] = (short)f2bf(zb[(size_t)c << 10]);
            }
            Z[pt][c0] = a;
        }
    }

    const int kbase = chalf * 4096 + wave * 512;
    for (int it = 0; it < 16; ++it) {
        int n0 = kbase + it * 32;
        const unsigned short* bb = cb16 + (size_t)(n0 + col) * EDIM + q * 8;
        f4v zz = {0.f, 0.f, 0.f, 0.f};
        f4v acc[4][2];
        #pragma unroll
        for (int pt = 0; pt < 4; ++pt) { acc[pt][0] = zz; acc[pt][1] = zz; }
        #pragma unroll
        for (int c0 = 0; c0 < 8; ++c0) {
            s8v C0 = *(const s8v*)(bb + c0 * 32);
            s8v C1 = *(const s8v*)(bb + 16 * EDIM + c0 * 32);
            #pragma unroll
            for (int pt = 0; pt < 4; ++pt) {
                acc[pt][0] = __builtin_amdgcn_mfma_f32_16x16x32_bf16(C0, Z[pt][c0], acc[pt][0], 0, 0, 0);
                acc[pt][1] = __builtin_amdgcn_mfma_f32_16x16x32_bf16(C1, Z[pt][c0], acc[pt][1], 0, 0, 0);
            }
        }
        int gbase = chalf * 256 + wave * 32 + it * 2;
        #pragma unroll
        for (int pt = 0; pt < 4; ++pt) {
            #pragma unroll
            for (int s = 0; s < 2; ++s) {
                f4v a = acc[pt][s];
                float mx = fmaxf(fmaxf(a[0], a[1]), fmaxf(a[2], a[3]));
                mx = fmaxf(mx, __shfl_xor(mx, 16));
                mx = fmaxf(mx, __shfl_xor(mx, 32));
                if (q == 0)
                    gmin[(size_t)((mb >> 4) + pt) * 8192 + (gbase + s) * 16 + col] =
                        f2bf_down(-2.0f * mx);
            }
        }
    }
}

// K2: rescore + fused loss (r16 proven version, UNCHANGED).
__global__ __launch_bounds__(256) void vq_phase2(const float* __restrict__ z,
                                                 const float* __restrict__ cb,
                                                 const float* __restrict__ esum32,
                                                 const unsigned short* __restrict__ gmin,
                                                 unsigned int* __restrict__ idxw,
                                                 float* __restrict__ lossparts) {
    __shared__ float zt[32 * 260];
    __shared__ unsigned short gm[NGRP * 33];
    __shared__ float zs[32];
    __shared__ int pq;
    int t = threadIdx.x;
    int wave = t >> 6, lane = t & 63;
    int p0 = blockIdx.x * 32;
    int bb = p0 >> 10, inner = p0 & 1023;

    if (t == 0) pq = 0;
    const float* zb = z + (((size_t)bb * 256) << 10) + inner;
    #pragma unroll
    for (int i = 0; i < 8; ++i) {
        int job = i * 256 + t;
        int c = job >> 3, qq = job & 7;      // 8 threads cover one 128B row
        f4 v = *(const f4*)(zb + ((size_t)c << 10) + qq * 4);
        #pragma unroll
        for (int e = 0; e < 4; ++e) zt[(qq * 4 + e) * 260 + c] = v[e];
    }
    const unsigned short* gsrc = gmin + (size_t)(2 * blockIdx.x) * 8192;
    #pragma unroll
    for (int j = 0; j < 8; ++j) {
        int li8 = (j * 256 + t) * 8;         // u16 offset, 16B-aligned, <16384
        s8v v = *(const s8v*)(gsrc + li8);
        int h = li8 >> 13, rem = li8 & 8191; // h in {0,1}
        int g = rem >> 4, r0 = rem & 15;     // r0 in {0,8}
        #pragma unroll
        for (int e = 0; e < 8; ++e) gm[g * 33 + h * 16 + r0 + e] = (unsigned short)v[e];
    }
    __syncthreads();
    if (t < 32) {
        const float* a = zt + t * 260;
        zs[t] = __fadd_rn(np_pw128sq(a), np_pw128sq(a + 128));  // np zsum
    }
    __syncthreads();

#define DOT_TAIL(sv) do { sv += __shfl_xor(sv, 1); sv += __shfl_xor(sv, 2); } while (0)
#define MERGE(dv, kv) do { if ((dv) < bd || ((dv) == bd && (kv) < bk)) { bd = (dv); bk = (kv); } } while (0)

    float wls = 0.f;                          // per-lane loss partial
    while (true) {
        int p;
        if (lane == 0) p = atomicAdd(&pq, 1);
        p = __shfl(p, 0);
        if (p >= 32) break;

        float lmin = 3.0e38f;
        #pragma unroll
        for (int j = 0; j < 8; ++j) lmin = fminf(lmin, bf2f(gm[(lane * 8 + j) * 33 + p]));
        #pragma unroll
        for (int m = 1; m < 64; m <<= 1) lmin = fminf(lmin, __shfl_xor(lmin, m));
        float thr = lmin + MARGIN;
        float zsp = zs[p];
        const f4* zr = (const f4*)(zt + p * 260) + (lane & 3);

        float bd = 3.0e38f; int bk = 0x7FFFFFFF;
        int pend = -1;
        for (int j = 0; j < 8; ++j) {
            unsigned long long mask = __ballot(bf2f(gm[(lane * 8 + j) * 33 + p]) <= thr);
            while (mask) {
                int lb = __builtin_ctzll(mask); mask &= mask - 1;
                int g = lb * 8 + j;
                if (pend < 0) { pend = g; continue; }
                int k1 = pend * 16 + (lane >> 2), k2 = g * 16 + (lane >> 2);
                const f4* c1 = (const f4*)(cb + (size_t)k1 * EDIM) + (lane & 3);
                const f4* c2 = (const f4*)(cb + (size_t)k2 * EDIM) + (lane & 3);
                double a0 = 0.0, a1 = 0.0, a2 = 0.0, a3 = 0.0;
                double b0 = 0.0, b1 = 0.0, b2 = 0.0, b3 = 0.0;
                #pragma unroll
                for (int i = 0; i < 16; ++i) {
                    f4 x = zr[i * 4], y1 = c1[i * 4], y2 = c2[i * 4];
                    a0 = fma((double)x[0], (double)y1[0], a0);
                    b0 = fma((double)x[0], (double)y2[0], b0);
                    a1 = fma((double)x[1], (double)y1[1], a1);
                    b1 = fma((double)x[1], (double)y2[1], b1);
                    a2 = fma((double)x[2], (double)y1[2], a2);
                    b2 = fma((double)x[2], (double)y2[2], b2);
                    a3 = fma((double)x[3], (double)y1[3], a3);
                    b3 = fma((double)x[3], (double)y2[3], b3);
                }
                double s1 = (a0 + a1) + (a2 + a3);
                double s2 = (b0 + b1) + (b2 + b3);
                DOT_TAIL(s1); DOT_TAIL(s2);
                float E1 = (float)s1, E2 = (float)s2;
                float d1 = __fsub_rn(__fadd_rn(zsp, esum32[k1]), __fmul_rn(2.0f, E1));
                float d2 = __fsub_rn(__fadd_rn(zsp, esum32[k2]), __fmul_rn(2.0f, E2));
                MERGE(d1, k1); MERGE(d2, k2);
                pend = -1;
            }
        }
        if (pend >= 0) {   // leftover single rescore (exact r6 body)
            int k = pend * 16 + (lane >> 2);
            const f4* cr = (const f4*)(cb + (size_t)k * EDIM) + (lane & 3);
            double a0 = 0.0, a1 = 0.0, a2 = 0.0, a3 = 0.0;
            #pragma unroll
            for (int i = 0; i < 16; ++i) {
                f4 x = zr[i * 4], y = cr[i * 4];
                a0 = fma((double)x[0], (double)y[0], a0);
                a1 = fma((double)x[1], (double)y[1], a1);
                a2 = fma((double)x[2], (double)y[2], a2);
                a3 = fma((double)x[3], (double)y[3], a3);
            }
            double s = (a0 + a1) + (a2 + a3);
            DOT_TAIL(s);
            float E = (float)s;
            float d = __fsub_rn(__fadd_rn(zsp, esum32[k]), __fmul_rn(2.0f, E));
            MERGE(d, k);
        }
        #pragma unroll
        for (int m = 1; m < 64; m <<= 1) {
            float od = __shfl_xor(bd, m); int ok = __shfl_xor(bk, m);
            if (od < bd || (od == bd && ok < bk)) { bd = od; bk = ok; }
        }
        if (lane == 0) idxw[p0 + p] = (unsigned int)bk;

        float s0 = 0.f;
        #pragma unroll
        for (int e = 0; e < 4; ++e) {
            float cv = cb[(size_t)bk * EDIM + lane + 64 * e];
            float zv = zt[p * 260 + lane + 64 * e];
            float dx = cv - zv; s0 = fmaf(dx, dx, s0);
        }
        wls += s0;
    }
    #pragma unroll
    for (int m = 1; m < 64; m <<= 1) wls += __shfl_xor(wls, m);
    if (lane == 0)
        atomicAdd(&lossparts[(((int)blockIdx.x << 2) + wave) & 63], wls);
#undef MERGE
#undef DOT_TAIL
}

// K3: pure scatter (r16 proven, UNCHANGED): z_q, indices, loss scalar.
__global__ __launch_bounds__(256) void vq_emit(const float* __restrict__ cb,
                                               const unsigned int* __restrict__ idxw,
                                               const float* __restrict__ lossparts,
                                               float* __restrict__ outf) {
    __shared__ float qrow[1024 * 17];        // [p][16ch] pad 17
    __shared__ unsigned int lidx[1024];
    int t = threadIdx.x;
    int gtid = blockIdx.x * 256 + t;
    if (gtid < N_PIX) outf[ZQ_ELEMS + 1 + gtid] = (float)(idxw[gtid] & (NE - 1));
    if (blockIdx.x == 0 && t < 64) {
        double v = (double)lossparts[t];
        #pragma unroll
        for (int m = 1; m < 64; m <<= 1) v += __shfl_xor(v, m);
        if (t == 0) outf[ZQ_ELEMS] = 1.25f * (float)(v * (1.0 / 4194304.0));
    }

    int b = blockIdx.x >> 4;                 // image
    int c0 = (blockIdx.x & 15) * 16;         // channel chunk

    #pragma unroll
    for (int j = 0; j < 4; ++j)
        lidx[j * 256 + t] = idxw[b * 1024 + j * 256 + t] & (NE - 1);
    __syncthreads();
    #pragma unroll
    for (int j = 0; j < 16; ++j) {
        int p = j * 64 + (t >> 2);
        f4 v = *(const f4*)(cb + (size_t)lidx[p] * EDIM + c0 + (t & 3) * 4);
        #pragma unroll
        for (int e = 0; e < 4; ++e) qrow[p * 17 + (t & 3) * 4 + e] = v[e];
    }
    __syncthreads();

    size_t base = (size_t)blockIdx.x * 16384;
    #pragma unroll
    for (int i = 0; i < 16; ++i) {           // ch chunk i, px = t*4..t*4+3
        f4 v;
        #pragma unroll
        for (int e = 0; e < 4; ++e) v[e] = qrow[(t * 4 + e) * 17 + i];
        *(f4*)&outf[base + (size_t)i * 1024 + t * 4] = v;
    }
}

extern "C" void kernel_launch(void* const* d_in, const int* in_sizes, int n_in,
                              void* d_out, int out_size, void* d_ws, size_t ws_size,
                              hipStream_t stream) {
    const float* z  = (const float*)d_in[0];   // f32 [16,256,32,32]
    const float* cb = (const float*)d_in[1];   // f32 [8192,256]
    float* outf = (float*)d_out;               // f32 [z_q | loss | indices]
    // gmin scratch (1024 chunks x 512 g x 16 px, u16 = 16.78 MB) lives in the
    // z_q chunk of d_out between phase1 and phase2; vq_emit overwrites it.
    unsigned short* gmin = (unsigned short*)d_out;

    char* w = (char*)d_ws;
    unsigned short* cb16     = (unsigned short*)w;             //  4,194,304 B
    float*          esum32   = (float*)(w + 4194304);          //     32,768 B
    unsigned int*   idxw     = (unsigned int*)(w + 4227072);   //     65,536 B
    float*          lossparts= (float*)(w + 4292608);          //        256 B (64 f32)
    unsigned short* z16      = (unsigned short*)(w + 4292864); //  8,388,608 B -> 12,681,472

    if (ws_size < 4292864) return;  // diagnostic: all-zero out => ws too small
    const bool big_ws = (ws_size >= 12681472);

    vq_pre<<<1280, 256, 0, stream>>>(z, cb, z16, cb16, esum32, lossparts, big_ws ? 1 : 0);
    if (big_ws) {
        vq_phase1g<<<(NE / 256) * (N_PIX / 1024), 512, 0, stream>>>(cb16, z16, gmin);
    } else {
        vq_phase1 <<<(N_PIX / 64) * 2, 512, 0, stream>>>(z, cb16, gmin);
    }
    vq_phase2  <<<N_PIX / 32, 256, 0, stream>>>(z, cb, esum32, gmin, idxw, lossparts);
    vq_emit    <<<256, 256, 0, stream>>>(cb, idxw, lossparts, outf);
}